// Round 10
// baseline (129.542 us; speedup 1.0000x reference)
//
#include <hip/hip_runtime.h>
#include <hip/hip_fp16.h>
#include <math.h>

// GraspCVAE loss, MI355X — round 10 (round 9 + compile fix).
// R9 failed to compile: ROCm 7.2 hip_fp16.h has no __hmin2. The hardware op
// (v_pk_min_f16) exists; emit it via inline asm with uint32 bit-casts.
// Everything else identical to R9's plan:
//   * hand->obj NN and prior-NN are value-only mins -> packed fp16
//     (v_pk_fma_f16 via __hfma2 + v_pk_min_f16 via asm), 2 candidates/inst.
//   * obj-side R/G argmin stays fp32 (cmap threshold 2.5e-5 on d2 + 10-bit
//     index packing need fp32 mantissa).
// Structure: mega1 (768 blks, plain slice stores, block 0 zeroes accs)
//         -> mega2 (482 blks, slice-reduce + fused final).

#define NB 32
#define NH 778
#define NO 3000
#define NZ 64
#define NP 204

#define P_OBJ 4
#define OBJ_PTS 1024
#define OBJ_TILES 3                   // ceil(3000/1024)
#define JSPLIT 4
#define JCH 195                       // ceil(778/4)
#define HC 12                         // hand-side obj chunks
#define HCS 250                       // 3000/12
#define HCP 125                       // HCS/2 half2 pairs
#define OBJ_BLKS (NB * OBJ_TILES * JSPLIT)    // 384
#define HAND_BLKS (NB * HC)                   // 384
#define T2 12                         // mega2 obj tiles (256 pts)
#define FIN_OBJ_BLKS (NB * T2)                // 384
#define FIN_TAIL_BLKS ((NB * NH + 255) / 256) // 98
#define FIN_BLKS (FIN_OBJ_BLKS + FIN_TAIL_BLKS) // 482

#define NKEY (NB * NO)                // 96000
#define NHT  (NB * NH)                // 24896

typedef unsigned int uint32;

// original order (PATH C)
__device__ __constant__ int c_prior[NP] = {
  697,698,699,700,712,713,714,715,737,738,739,740,741,743,744,745,746,748,749,750,
  753,754,755,756,757,758,759,760,761,762,763,764,765,766,767,768,
  46,47,48,49,164,165,166,167,194,195,223,237,238,280,281,298,301,317,320,323,
  324,325,326,327,328,329,330,331,332,333,340,341,342,343,344,345,346,347,348,349,
  350,351,352,353,354,355,
  356,357,358,359,375,376,386,387,396,397,402,403,413,429,433,434,435,436,437,438,
  439,440,441,442,443,444,452,453,454,455,456,459,460,461,462,463,464,465,466,467,
  468,469,470,471,484,485,486,496,497,506,507,513,514,524,545,546,547,548,549,550,
  551,552,553,555,563,564,565,566,567,570,572,573,574,575,576,577,578,
  580,581,582,583,600,601,602,614,615,624,625,630,631,641,663,664,665,666,667,668,
  670,672,680,681,682,683,684,686,687,688,689,690,691,692,693,694,695,
  73,96,98,99,772,774,775,777
};

// sorted; per-split offsets [0,13) [13,58) [58,131) [131,204)
__device__ __constant__ int c_prior_sorted[NP] = {
  46,47,48,49,73,96,98,99,164,165,166,167,194,
  195,223,237,238,280,281,298,301,317,320,323,324,325,326,327,328,329,330,331,
  332,333,340,341,342,343,344,345,346,347,348,349,350,351,352,353,354,355,356,
  357,358,359,375,376,386,387,
  396,397,402,403,413,429,433,434,435,436,437,438,439,440,441,442,443,444,452,
  453,454,455,456,459,460,461,462,463,464,465,466,467,468,469,470,471,484,485,
  486,496,497,506,507,513,514,524,545,546,547,548,549,550,551,552,553,555,563,
  564,565,566,567,570,572,573,574,575,576,577,578,580,581,582,583,
  600,601,602,614,615,624,625,630,631,641,663,664,665,666,667,668,670,672,680,
  681,682,683,684,686,687,688,689,690,691,692,693,694,695,697,698,699,700,712,
  713,714,715,737,738,739,740,741,743,744,745,746,748,749,750,753,754,755,756,
  757,758,759,760,761,762,763,764,765,766,767,768,772,774,775,777
};
__device__ __constant__ int c_psplit[JSPLIT + 1] = {0, 13, 58, 131, 204};

__device__ inline float wave_sum(float v) {
  v += __shfl_down(v, 32);
  v += __shfl_down(v, 16);
  v += __shfl_down(v, 8);
  v += __shfl_down(v, 4);
  v += __shfl_down(v, 2);
  v += __shfl_down(v, 1);
  return v;
}

__device__ inline float packkey(float t, int j) {
  return __uint_as_float((__float_as_uint(t) & 0xFFFFFC00u) | (uint32)j);
}
__device__ inline __half2 h2bcast(float f) {
  __half h = __float2half(f);
  return __halves2half2(h, h);
}
// ROCm 7.2 lacks __hmin2; emit v_pk_min_f16 directly
__device__ inline __half2 hmin2(__half2 a, __half2 b) {
  union { __half2 h; uint32 u; } ua, ub, ur;
  ua.h = a; ub.h = b;
  asm("v_pk_min_f16 %0, %1, %2" : "=v"(ur.u) : "v"(ua.u), "v"(ub.u));
  return ur.h;
}

// ======================= dispatch 1: mega1 =======================
// accs: 0 penetr,1 npts,2 contact,3 consist,4 loss_o,5 loss_h,6 recon_sq,7 kld,8 cnt
__global__ __launch_bounds__(256) void mega1a(
    const float* __restrict__ recon, const float* __restrict__ gt,
    const float* __restrict__ obj,
    float* __restrict__ keyR, float* __restrict__ keyG,
    float* __restrict__ priorK,
    float* __restrict__ minHR, float* __restrict__ minHG,
    float* __restrict__ accs)
{
  const int bid = blockIdx.x;
  const int tid = threadIdx.x;

  if (bid == 0 && tid < 16) accs[tid] = 0.0f;

  if (bid < OBJ_BLKS) {
    // ---- obj -> hand NN (fp32, argmin) + fp16 partial prior-NN ----
    __shared__ float4 shA[JCH];   // recon split
    __shared__ float4 shB[JCH];   // gt split
    __shared__ __half2 shPx[37], shPy[37], shPz[37], shPw[37];
    const int b     = bid / (OBJ_TILES * JSPLIT);
    const int rem   = bid % (OBJ_TILES * JSPLIT);
    const int tile  = rem / JSPLIT;
    const int split = rem % JSPLIT;
    const int jbase = split * JCH;
    const int jcnt  = (NH - jbase < JCH) ? (NH - jbase) : JCH;

    for (int i = tid; i < jcnt; i += 256) {
      const float* p = recon + ((size_t)b * NH + jbase + i) * 3;
      float x = p[0], y = p[1], z = p[2];
      shA[i] = make_float4(x, y, z, x*x + y*y + z*z);
      const float* q = gt + ((size_t)b * NH + jbase + i) * 3;
      float gx = q[0], gy = q[1], gz = q[2];
      shB[i] = make_float4(gx, gy, gz, gx*gx + gy*gy + gz*gz);
    }
    // stage prior subset as packed half2 pairs
    const int pk0 = c_psplit[split], pk1 = c_psplit[split + 1];
    const int pcnt = pk1 - pk0;                 // 13,45,73,73
    const int ppairs = (pcnt + 1) >> 1;
    if (tid < ppairs) {
      int k0 = pk0 + 2 * tid;
      int k1 = (2 * tid + 1 < pcnt) ? (k0 + 1) : k0;   // duplicate last if odd
      const float* p0 = recon + ((size_t)b * NH + c_prior_sorted[k0]) * 3;
      const float* p1 = recon + ((size_t)b * NH + c_prior_sorted[k1]) * 3;
      float x0 = p0[0], y0 = p0[1], z0 = p0[2];
      float x1 = p1[0], y1 = p1[1], z1 = p1[2];
      shPx[tid] = __halves2half2(__float2half(x0), __float2half(x1));
      shPy[tid] = __halves2half2(__float2half(y0), __float2half(y1));
      shPz[tid] = __halves2half2(__float2half(z0), __float2half(z1));
      shPw[tid] = __halves2half2(__float2half(x0*x0 + y0*y0 + z0*z0),
                                 __float2half(x1*x1 + y1*y1 + z1*z1));
    }
    __syncthreads();

    float nx[P_OBJ], ny[P_OBJ], nz[P_OBJ];
    int ob[P_OBJ]; bool val[P_OBJ];
    #pragma unroll
    for (int m = 0; m < P_OBJ; ++m) {
      int o = tile * OBJ_PTS + m * 256 + tid;
      ob[m] = o; val[m] = (o < NO);
      float x = 0.f, y = 0.f, z = 0.f;
      if (val[m]) {
        const float* op = obj + ((size_t)b * NO + o) * 3;
        x = op[0]; y = op[1]; z = op[2];
      }
      nx[m] = -2.f * x; ny[m] = -2.f * y; nz[m] = -2.f * z;
    }

    float bR[P_OBJ], bG[P_OBJ];
    #pragma unroll
    for (int m = 0; m < P_OBJ; ++m) { bR[m] = 3.4e38f; bG[m] = 3.4e38f; }

    int i = 0;
    for (; i + 1 < jcnt; i += 2) {
      float4 h0 = shA[i], h1 = shA[i + 1];
      #pragma unroll
      for (int m = 0; m < P_OBJ; ++m) {
        float t0 = fmaf(nx[m], h0.x, h0.w); t0 = fmaf(ny[m], h0.y, t0); t0 = fmaf(nz[m], h0.z, t0);
        float t1 = fmaf(nx[m], h1.x, h1.w); t1 = fmaf(ny[m], h1.y, t1); t1 = fmaf(nz[m], h1.z, t1);
        bR[m] = fminf(bR[m], fminf(packkey(t0, jbase + i), packkey(t1, jbase + i + 1)));
      }
      float4 g0 = shB[i], g1 = shB[i + 1];
      #pragma unroll
      for (int m = 0; m < P_OBJ; ++m) {
        float t0 = fmaf(nx[m], g0.x, g0.w); t0 = fmaf(ny[m], g0.y, t0); t0 = fmaf(nz[m], g0.z, t0);
        float t1 = fmaf(nx[m], g1.x, g1.w); t1 = fmaf(ny[m], g1.y, t1); t1 = fmaf(nz[m], g1.z, t1);
        bG[m] = fminf(bG[m], fminf(packkey(t0, jbase + i), packkey(t1, jbase + i + 1)));
      }
    }
    if (i < jcnt) {
      float4 h0 = shA[i];
      float4 g0 = shB[i];
      #pragma unroll
      for (int m = 0; m < P_OBJ; ++m) {
        float t0 = fmaf(nx[m], h0.x, h0.w); t0 = fmaf(ny[m], h0.y, t0); t0 = fmaf(nz[m], h0.z, t0);
        bR[m] = fminf(bR[m], packkey(t0, jbase + i));
        float u0 = fmaf(nx[m], g0.x, g0.w); u0 = fmaf(ny[m], g0.y, u0); u0 = fmaf(nz[m], g0.z, u0);
        bG[m] = fminf(bG[m], packkey(u0, jbase + i));
      }
    }

    // fp16 partial prior-NN (value-only min)
    __half2 pnx[P_OBJ], pny[P_OBJ], pnz[P_OBJ], pmin[P_OBJ];
    #pragma unroll
    for (int m = 0; m < P_OBJ; ++m) {
      pnx[m] = h2bcast(nx[m]); pny[m] = h2bcast(ny[m]); pnz[m] = h2bcast(nz[m]);
      pmin[m] = h2bcast(65000.f);
    }
    for (int k = 0; k < ppairs; ++k) {
      __half2 px = shPx[k], py = shPy[k], pz = shPz[k], pw = shPw[k];
      #pragma unroll
      for (int m = 0; m < P_OBJ; ++m) {
        __half2 t = __hfma2(pnx[m], px, pw);
        t = __hfma2(pny[m], py, t);
        t = __hfma2(pnz[m], pz, t);
        pmin[m] = hmin2(pmin[m], t);
      }
    }

    #pragma unroll
    for (int m = 0; m < P_OBJ; ++m) {
      if (!val[m]) continue;
      const size_t idx = (size_t)split * NKEY + (size_t)b * NO + ob[m];
      keyR[idx] = bR[m];
      keyG[idx] = bG[m];
      priorK[idx] = fminf(__low2float(pmin[m]), __high2float(pmin[m]));
    }
  } else {
    // ---- hand -> obj NN, fp16 packed (value-only min), 12 chunks ----
    __shared__ __half2 sOx[HCP], sOy[HCP], sOz[HCP], sOw[HCP];
    const int bid2 = bid - OBJ_BLKS;
    const int oc = bid2 % HC;
    const int b  = bid2 / HC;

    const float* Ob = obj + ((size_t)b * NO + oc * HCS) * 3;
    for (int p = tid; p < HCP; p += 256) {
      float x0 = Ob[6*p],   y0 = Ob[6*p+1], z0 = Ob[6*p+2];
      float x1 = Ob[6*p+3], y1 = Ob[6*p+4], z1 = Ob[6*p+5];
      sOx[p] = __halves2half2(__float2half(x0), __float2half(x1));
      sOy[p] = __halves2half2(__float2half(y0), __float2half(y1));
      sOz[p] = __halves2half2(__float2half(z0), __float2half(z1));
      sOw[p] = __halves2half2(__float2half(x0*x0 + y0*y0 + z0*z0),
                              __float2half(x1*x1 + y1*y1 + z1*z1));
    }
    __syncthreads();

    __half2 nrx[4], nry[4], nrz[4];
    __half2 ngx[4], ngy[4], ngz[4];
    bool val[4];
    #pragma unroll
    for (int m = 0; m < 4; ++m) {
      int j = m * 256 + tid;
      val[m] = (j < NH);
      float rx = 0.f, ry = 0.f, rz = 0.f, gx = 0.f, gy = 0.f, gz = 0.f;
      if (val[m]) {
        const float* rp = recon + ((size_t)b * NH + j) * 3;
        const float* gp = gt    + ((size_t)b * NH + j) * 3;
        rx = rp[0]; ry = rp[1]; rz = rp[2];
        gx = gp[0]; gy = gp[1]; gz = gp[2];
      }
      nrx[m] = h2bcast(-2.f*rx); nry[m] = h2bcast(-2.f*ry); nrz[m] = h2bcast(-2.f*rz);
      ngx[m] = h2bcast(-2.f*gx); ngy[m] = h2bcast(-2.f*gy); ngz[m] = h2bcast(-2.f*gz);
    }

    __half2 mR[4], mG[4];
    #pragma unroll
    for (int m = 0; m < 4; ++m) { mR[m] = h2bcast(65000.f); mG[m] = h2bcast(65000.f); }

    for (int p = 0; p < HCP; ++p) {
      __half2 oxp = sOx[p], oyp = sOy[p], ozp = sOz[p], owp = sOw[p];
      #pragma unroll
      for (int m = 0; m < 4; ++m) {
        __half2 t = __hfma2(nrx[m], oxp, owp);
        t = __hfma2(nry[m], oyp, t);
        t = __hfma2(nrz[m], ozp, t);
        mR[m] = hmin2(mR[m], t);
        __half2 u = __hfma2(ngx[m], oxp, owp);
        u = __hfma2(ngy[m], oyp, u);
        u = __hfma2(ngz[m], ozp, u);
        mG[m] = hmin2(mG[m], u);
      }
    }

    #pragma unroll
    for (int m = 0; m < 4; ++m) {
      if (!val[m]) continue;
      int j = m * 256 + tid;
      const size_t idx = (size_t)oc * NHT + (size_t)b * NH + j;
      minHR[idx] = fminf(__low2float(mR[m]), __high2float(mR[m]));
      minHG[idx] = fminf(__low2float(mG[m]), __high2float(mG[m]));
    }
  }
}

// ======================= dispatch 2: mega2 (unchanged from R8) =======================
__global__ __launch_bounds__(256) void mega2a(
    const float* __restrict__ recon, const float* __restrict__ gt,
    const float* __restrict__ rnorm, const float* __restrict__ gnorm,
    const float* __restrict__ obj,
    const float* __restrict__ mean, const float* __restrict__ logv,
    const float* __restrict__ vw,
    const float* __restrict__ keyR, const float* __restrict__ keyG,
    const float* __restrict__ priorK,
    const float* __restrict__ minHR, const float* __restrict__ minHG,
    float* __restrict__ accs, float* __restrict__ out)
{
  __shared__ float red[4][5];
  const int bid = blockIdx.x;
  const int tid = threadIdx.x;
  const int lane = tid & 63, wv = tid >> 6;

  if (bid < FIN_OBJ_BLKS) {
    const int b = bid / T2;
    const int tile = bid % T2;
    const int o = tile * 256 + tid;
    float penetr = 0.f, nptsv = 0.f, contactv = 0.f, consistv = 0.f, lossov = 0.f;
    if (o < NO) {
      const float* op = obj + ((size_t)b * NO + o) * 3;
      const float ox = op[0], oy = op[1], oz = op[2];
      const float o2 = ox*ox + oy*oy + oz*oz;
      const size_t base = (size_t)b * NO + o;

      float kR = 3.4e38f, kG = 3.4e38f, bP = 3.4e38f;
      #pragma unroll
      for (int s = 0; s < JSPLIT; ++s) {
        kR = fminf(kR, keyR[(size_t)s * NKEY + base]);
        kG = fminf(kG, keyG[(size_t)s * NKEY + base]);
        bP = fminf(bP, priorK[(size_t)s * NKEY + base]);
      }
      uint32 kRb = __float_as_uint(kR), kGb = __float_as_uint(kG);
      int idxR = (int)(kRb & 0x3FFu), idxG = (int)(kGb & 0x3FFu);
      float d2R = fmaxf(__uint_as_float(kRb & 0xFFFFFC00u) + o2, 0.f);
      float d2G = fmaxf(__uint_as_float(kGb & 0xFFFFFC00u) + o2, 0.f);
      float d2P = fmaxf(bP + o2, 0.f);

      const float* hR = recon + ((size_t)b * NH + idxR) * 3;
      const float* nR = rnorm + ((size_t)b * NH + idxR) * 3;
      float dotR = (ox - hR[0]) * nR[0] + (oy - hR[1]) * nR[1] + (oz - hR[2]) * nR[2];
      const float* hG = gt + ((size_t)b * NH + idxG) * 3;
      const float* nG = gnorm + ((size_t)b * NH + idxG) * 3;
      float dotG = (ox - hG[0]) * nG[0] + (oy - hG[1]) * nG[1] + (oz - hG[2]) * nG[2];

      float sgnR = (dotR > 0.f) ? 1.f : ((dotR < 0.f) ? -1.f : 0.f);
      float sgnG = (dotG > 0.f) ? 1.f : ((dotG < 0.f) ? -1.f : 0.f);
      float sR_ = sqrtf(d2R), sG_ = sqrtf(d2G);
      float o2h = sR_ * sgnR, o2hg = sG_ * sgnG;

      bool interior = dotR < 0.f;
      bool cmap = sG_ < 0.005f;
      bool rcmap = sR_ < 0.005f;

      penetr   = interior ? d2R : 0.f;
      nptsv    = cmap ? 1.f : 0.f;
      contactv = cmap ? d2P : 0.f;
      consistv = (cmap && rcmap) ? 1.f : 0.f;
      float w = (o2h < 0.f) ? 1.5f
              : (((o2hg < 0.01f) && (o2hg > -0.005f)) ? 1.f : 0.1f);
      lossov = fabsf(o2h - o2hg) * w;
    }

    float vals[5] = {penetr, nptsv, contactv, consistv, lossov};
    #pragma unroll
    for (int q = 0; q < 5; ++q) {
      float s = wave_sum(vals[q]);
      if (lane == 0) red[wv][q] = s;
    }
    __syncthreads();
    if (tid < 5) {
      float s = red[0][tid] + red[1][tid] + red[2][tid] + red[3][tid];
      atomicAdd(&accs[tid], s);
    }
  } else {
    const int t = (bid - FIN_OBJ_BLKS) * 256 + tid;
    float lossh = 0.f, rsum = 0.f, ksum = 0.f;
    if (t < NB * NH) {
      const float* rp = recon + (size_t)t * 3;
      const float* gp = gt + (size_t)t * 3;
      float rx = rp[0], ry = rp[1], rz = rp[2];
      float gx = gp[0], gy = gp[1], gz = gp[2];
      float d0 = rx - gx, d1 = ry - gy, d2 = rz - gz;
      rsum = d0*d0 + d1*d1 + d2*d2;

      float tR[HC], tG[HC];
      #pragma unroll
      for (int c = 0; c < HC; ++c) {
        tR[c] = minHR[(size_t)c * NHT + t];
        tG[c] = minHG[(size_t)c * NHT + t];
      }
      float mRt = tR[0], mGt = tG[0];
      #pragma unroll
      for (int c = 1; c < HC; ++c) {
        mRt = fminf(mRt, tR[c]);
        mGt = fminf(mGt, tG[c]);
      }
      float r2 = rx*rx + ry*ry + rz*rz;
      float g2 = gx*gx + gy*gy + gz*gz;
      float d2Rh = fmaxf(mRt + r2, 0.f);
      float d2Gh = fmaxf(mGt + g2, 0.f);
      int j = t % NH;
      lossh = fabsf(sqrtf(d2Rh) - sqrtf(d2Gh)) * powf(vw[j], 0.4f);
    }
    if (t < NB * NZ) {
      float m = mean[t], lv = logv[t];
      ksum = 1.f + lv - m * m - expf(lv);
    }
    float vals[3] = {lossh, rsum, ksum};
    #pragma unroll
    for (int q = 0; q < 3; ++q) {
      float s = wave_sum(vals[q]);
      if (lane == 0) red[wv][q] = s;
    }
    __syncthreads();
    if (tid < 3) {
      float s = red[0][tid] + red[1][tid] + red[2][tid] + red[3][tid];
      atomicAdd(&accs[5 + tid], s);
    }
  }

  __syncthreads();
  if (tid == 0) {
    __threadfence();
    int* cnt = (int*)(accs + 8);
    int old = atomicAdd(cnt, 1);
    if (old == FIN_BLKS - 1) {
      float a[8];
      #pragma unroll
      for (int q = 0; q < 8; ++q) a[q] = atomicAdd(&accs[q], 0.0f);
      const float recon_loss = a[6] / (float)NB;
      const float kld = -0.5f * a[7] / (float)NB * 10.f;
      const float penetr = 100.f * a[0] / (float)NB;
      const float npts = a[1];
      const float contact = (npts > 0.f) ? (3000.f * a[2] / ((float)NB * npts)) : 0.f;
      const float consistency = -5.f * a[3] / (npts + 0.0001f);
      const float lossh = 35.f * (1.f - 0.005f) * (a[5] / (float)(NB * NH));
      const float losso = 30.f * (1.f - 0.005f) * (a[4] / (float)(NB * NO));
      out[0] = recon_loss + 0.1f * kld + 1000.f * penetr + 10.f * contact
             + 10.f * consistency + lossh + losso;
    }
  }
}

// =========================== PATH C (tiny ws fallback) ===========================
__global__ __launch_bounds__(256) void obj_mono(
    const float* __restrict__ recon, const float* __restrict__ gt,
    const float* __restrict__ rnorm, const float* __restrict__ gnorm,
    const float* __restrict__ obj, float* __restrict__ accs)
{
  __shared__ float4 sR[NH];
  __shared__ float4 sG[NH];
  __shared__ float red[4][5];
  const int b = blockIdx.x / 12;
  const int tile = blockIdx.x % 12;
  const int tid = threadIdx.x;
  for (int i = tid; i < NH; i += 256) {
    const float* p = recon + ((size_t)b * NH + i) * 3;
    float x = p[0], y = p[1], z = p[2];
    sR[i] = make_float4(x, y, z, x*x + y*y + z*z);
    const float* q = gt + ((size_t)b * NH + i) * 3;
    float gx = q[0], gy = q[1], gz = q[2];
    sG[i] = make_float4(gx, gy, gz, gx*gx + gy*gy + gz*gz);
  }
  __syncthreads();
  const int o = tile * 256 + tid;
  float penetr = 0.f, nptsv = 0.f, contactv = 0.f, consistv = 0.f, lossov = 0.f;
  if (o < NO) {
    const float* op = obj + ((size_t)b * NO + o) * 3;
    const float ox = op[0], oy = op[1], oz = op[2];
    const float nx = -2.f*ox, ny = -2.f*oy, nz = -2.f*oz;
    const float o2 = ox*ox + oy*oy + oz*oz;
    float bR = 3.4e38f, bG = 3.4e38f; int iR = 0, iG = 0;
    for (int i = 0; i < NH; ++i) {
      float4 h = sR[i];
      float t = fmaf(nx, h.x, h.w); t = fmaf(ny, h.y, t); t = fmaf(nz, h.z, t);
      if (t < bR) { bR = t; iR = i; }
      float4 g = sG[i];
      float u = fmaf(nx, g.x, g.w); u = fmaf(ny, g.y, u); u = fmaf(nz, g.z, u);
      if (u < bG) { bG = u; iG = i; }
    }
    float bP = 3.4e38f;
    for (int k = 0; k < NP; ++k) {
      float4 h = sR[c_prior[k]];
      float t = fmaf(nx, h.x, h.w); t = fmaf(ny, h.y, t); t = fmaf(nz, h.z, t);
      bP = fminf(bP, t);
    }
    float d2R = fmaxf(bR + o2, 0.f);
    float d2G = fmaxf(bG + o2, 0.f);
    float d2P = fmaxf(bP + o2, 0.f);
    float4 hR = sR[iR];
    const float* nR = rnorm + ((size_t)b * NH + iR) * 3;
    float dotR = (ox-hR.x)*nR[0] + (oy-hR.y)*nR[1] + (oz-hR.z)*nR[2];
    float4 hG = sG[iG];
    const float* nG = gnorm + ((size_t)b * NH + iG) * 3;
    float dotG = (ox-hG.x)*nG[0] + (oy-hG.y)*nG[1] + (oz-hG.z)*nG[2];
    float sgnR = (dotR > 0.f) ? 1.f : ((dotR < 0.f) ? -1.f : 0.f);
    float sgnG = (dotG > 0.f) ? 1.f : ((dotG < 0.f) ? -1.f : 0.f);
    float sR_ = sqrtf(d2R), sG_ = sqrtf(d2G);
    float o2h = sR_*sgnR, o2hg = sG_*sgnG;
    bool interior = dotR < 0.f;
    bool cmap = sG_ < 0.005f, rcmap = sR_ < 0.005f;
    penetr = interior ? d2R : 0.f;
    nptsv = cmap ? 1.f : 0.f;
    contactv = cmap ? d2P : 0.f;
    consistv = (cmap && rcmap) ? 1.f : 0.f;
    float w = (o2h < 0.f) ? 1.5f : (((o2hg < 0.01f) && (o2hg > -0.005f)) ? 1.f : 0.1f);
    lossov = fabsf(o2h - o2hg) * w;
  }
  float vals[5] = {penetr, nptsv, contactv, consistv, lossov};
  const int lane = tid & 63, wv = tid >> 6;
  for (int q = 0; q < 5; ++q) {
    float s = wave_sum(vals[q]);
    if (lane == 0) red[wv][q] = s;
  }
  __syncthreads();
  if (tid < 5) {
    float s = red[0][tid] + red[1][tid] + red[2][tid] + red[3][tid];
    atomicAdd(&accs[tid], s);
  }
}

__global__ __launch_bounds__(256) void hand_full(
    const float* __restrict__ recon, const float* __restrict__ gt,
    const float* __restrict__ obj, const float* __restrict__ vw,
    float* __restrict__ accs)
{
  __shared__ float4 sO[500];
  __shared__ float red[4];
  const int b = blockIdx.x >> 2;
  const int j = ((blockIdx.x & 3) << 8) + threadIdx.x;
  const bool valid = j < NH;
  float rx=0,ry=0,rz=0,gx=0,gy=0,gz=0;
  if (valid) {
    const float* rp = recon + ((size_t)b * NH + j) * 3;
    const float* gp = gt + ((size_t)b * NH + j) * 3;
    rx=rp[0];ry=rp[1];rz=rp[2]; gx=gp[0];gy=gp[1];gz=gp[2];
  }
  const float nrx=-2.f*rx, nry=-2.f*ry, nrz=-2.f*rz;
  const float ngx=-2.f*gx, ngy=-2.f*gy, ngz=-2.f*gz;
  const float r2 = rx*rx+ry*ry+rz*rz, g2 = gx*gx+gy*gy+gz*gz;
  float mR = 3.4e38f, mG = 3.4e38f;
  for (int oc = 0; oc < 6; ++oc) {
    __syncthreads();
    const float* Ob = obj + ((size_t)b * NO + oc * 500) * 3;
    for (int i = threadIdx.x; i < 500; i += 256) {
      float x = Ob[3*i], y = Ob[3*i+1], z = Ob[3*i+2];
      sO[i] = make_float4(x, y, z, x*x + y*y + z*z);
    }
    __syncthreads();
    if (valid) {
      for (int k = 0; k < 500; ++k) {
        float4 o4 = sO[k];
        float t = fmaf(nrx,o4.x,o4.w); t = fmaf(nry,o4.y,t); t = fmaf(nrz,o4.z,t);
        mR = fminf(mR, t);
        float u = fmaf(ngx,o4.x,o4.w); u = fmaf(ngy,o4.y,u); u = fmaf(ngz,o4.z,u);
        mG = fminf(mG, u);
      }
    }
  }
  float lossh = valid ? fabsf(sqrtf(fmaxf(mR+r2,0.f)) - sqrtf(fmaxf(mG+g2,0.f))) * powf(vw[j], 0.4f) : 0.f;
  const int lane = threadIdx.x & 63, wv = threadIdx.x >> 6;
  float s = wave_sum(lossh);
  if (lane == 0) red[wv] = s;
  __syncthreads();
  if (threadIdx.x == 0) atomicAdd(&accs[5], red[0]+red[1]+red[2]+red[3]);
}

__global__ __launch_bounds__(256) void tail_nomins(
    const float* __restrict__ recon, const float* __restrict__ gt,
    const float* __restrict__ mean, const float* __restrict__ logv,
    float* __restrict__ accs)
{
  __shared__ float red[4][2];
  const int t = blockIdx.x * 256 + threadIdx.x;
  float rsum = 0.f, ksum = 0.f;
  if (t < NB * NH) {
    const float* rp = recon + (size_t)t * 3;
    const float* gp = gt + (size_t)t * 3;
    float d0 = rp[0]-gp[0], d1 = rp[1]-gp[1], d2 = rp[2]-gp[2];
    rsum = d0*d0 + d1*d1 + d2*d2;
  }
  if (t < NB * NZ) {
    float m = mean[t], lv = logv[t];
    ksum = 1.f + lv - m*m - expf(lv);
  }
  float vals[2] = {rsum, ksum};
  const int lane = threadIdx.x & 63, wv = threadIdx.x >> 6;
  for (int q = 0; q < 2; ++q) {
    float s = wave_sum(vals[q]);
    if (lane == 0) red[wv][q] = s;
  }
  __syncthreads();
  if (threadIdx.x < 2) {
    float s = red[0][threadIdx.x] + red[1][threadIdx.x] + red[2][threadIdx.x] + red[3][threadIdx.x];
    atomicAdd(&accs[6 + threadIdx.x], s);
  }
}

__global__ void init_small(float* accs) {
  int t = threadIdx.x;
  if (t < 8) accs[t] = 0.0f;
}

__global__ void final_fb(const float* __restrict__ a, float* __restrict__ out) {
  const float recon_loss = a[6] / (float)NB;
  const float kld = -0.5f * a[7] / (float)NB * 10.f;
  const float penetr = 100.f * a[0] / (float)NB;
  const float npts = a[1];
  const float contact = (npts > 0.f) ? (3000.f * a[2] / ((float)NB * npts)) : 0.f;
  const float consistency = -5.f * a[3] / (npts + 0.0001f);
  const float lossh = 35.f * (1.f - 0.005f) * (a[5] / (float)(NB * NH));
  const float losso = 30.f * (1.f - 0.005f) * (a[4] / (float)(NB * NO));
  out[0] = recon_loss + 0.1f*kld + 1000.f*penetr + 10.f*contact + 10.f*consistency + lossh + losso;
}

extern "C" void kernel_launch(void* const* d_in, const int* in_sizes, int n_in,
                              void* d_out, int out_size, void* d_ws, size_t ws_size,
                              hipStream_t stream) {
  const float* recon = (const float*)d_in[0];
  const float* gt    = (const float*)d_in[1];
  const float* rnorm = (const float*)d_in[2];
  const float* gnorm = (const float*)d_in[3];
  const float* obj   = (const float*)d_in[4];
  const float* mean  = (const float*)d_in[5];
  const float* logv  = (const float*)d_in[6];
  const float* vw    = (const float*)d_in[7];
  float* out = (float*)d_out;

  float* accs   = (float*)d_ws;
  float* keyR   = (float*)((char*)d_ws + 256);
  float* keyG   = keyR + (size_t)JSPLIT * NKEY;
  float* priorK = keyG + (size_t)JSPLIT * NKEY;
  float* minHR  = priorK + (size_t)JSPLIT * NKEY;
  float* minHG  = minHR + (size_t)HC * NHT;
  const size_t neededA = 256 + (3ull * JSPLIT * NKEY + 2ull * HC * NHT) * sizeof(float);

  if (ws_size >= neededA) {
    mega1a<<<OBJ_BLKS + HAND_BLKS, 256, 0, stream>>>(
        recon, gt, obj, keyR, keyG, priorK, minHR, minHG, accs);
    mega2a<<<FIN_BLKS, 256, 0, stream>>>(
        recon, gt, rnorm, gnorm, obj, mean, logv, vw,
        keyR, keyG, priorK, minHR, minHG, accs, out);
  } else {
    init_small<<<1, 64, 0, stream>>>(accs);
    obj_mono<<<NB * 12, 256, 0, stream>>>(recon, gt, rnorm, gnorm, obj, accs);
    hand_full<<<NB * 4, 256, 0, stream>>>(recon, gt, obj, vw, accs);
    tail_nomins<<<(NB * NH + 255) / 256, 256, 0, stream>>>(recon, gt, mean, logv, accs);
    final_fb<<<1, 1, 0, stream>>>(accs, out);
  }
}

// Round 11
// 127.863 us; speedup vs baseline: 1.0131x; 1.0131x over previous
//
#include <hip/hip_runtime.h>
#include <math.h>

// GraspCVAE loss, MI355X — round 11.
// R10 (packed fp16) regressed: inline-asm v_pk_min_f16 broke scheduling and
// the 4x b32 LDS layout lost b128 vectorization (mega1 42->48us, VALUBusy
// 99.98->65%). Revert to R8's proven fp32 formulation; single change:
// obj-side register tile P_OBJ 4->6 (OBJ_TILES 3->2) to amortize ds_read_b128
// and loop overhead over more points. Hand side / mega2 / ws layout identical
// to R8 (121.26us, absmax 0.0).

#define NB 32
#define NH 778
#define NO 3000
#define NZ 64
#define NP 204

#define P_OBJ 6
#define OBJ_PTS (256 * P_OBJ)         // 1536
#define OBJ_TILES 2                   // ceil(3000/1536)
#define JSPLIT 4
#define JCH 195                       // ceil(778/4)
#define HC 12                         // hand-side obj chunks
#define HCS 250                       // 3000/12
#define OBJ_BLKS (NB * OBJ_TILES * JSPLIT)    // 256
#define HAND_BLKS (NB * HC)                   // 384
#define T2 12                         // mega2 obj tiles (256 pts)
#define FIN_OBJ_BLKS (NB * T2)                // 384
#define FIN_TAIL_BLKS ((NB * NH + 255) / 256) // 98
#define FIN_BLKS (FIN_OBJ_BLKS + FIN_TAIL_BLKS) // 482

#define NKEY (NB * NO)                // 96000
#define NHT  (NB * NH)                // 24896

typedef unsigned int uint32;

// original order (PATH C)
__device__ __constant__ int c_prior[NP] = {
  697,698,699,700,712,713,714,715,737,738,739,740,741,743,744,745,746,748,749,750,
  753,754,755,756,757,758,759,760,761,762,763,764,765,766,767,768,
  46,47,48,49,164,165,166,167,194,195,223,237,238,280,281,298,301,317,320,323,
  324,325,326,327,328,329,330,331,332,333,340,341,342,343,344,345,346,347,348,349,
  350,351,352,353,354,355,
  356,357,358,359,375,376,386,387,396,397,402,403,413,429,433,434,435,436,437,438,
  439,440,441,442,443,444,452,453,454,455,456,459,460,461,462,463,464,465,466,467,
  468,469,470,471,484,485,486,496,497,506,507,513,514,524,545,546,547,548,549,550,
  551,552,553,555,563,564,565,566,567,570,572,573,574,575,576,577,578,
  580,581,582,583,600,601,602,614,615,624,625,630,631,641,663,664,665,666,667,668,
  670,672,680,681,682,683,684,686,687,688,689,690,691,692,693,694,695,
  73,96,98,99,772,774,775,777
};

// sorted; per-JCH-split offsets: [0,13) [13,58) [58,131) [131,204)
__device__ __constant__ int c_prior_sorted[NP] = {
  46,47,48,49,73,96,98,99,164,165,166,167,194,
  195,223,237,238,280,281,298,301,317,320,323,324,325,326,327,328,329,330,331,
  332,333,340,341,342,343,344,345,346,347,348,349,350,351,352,353,354,355,356,
  357,358,359,375,376,386,387,
  396,397,402,403,413,429,433,434,435,436,437,438,439,440,441,442,443,444,452,
  453,454,455,456,459,460,461,462,463,464,465,466,467,468,469,470,471,484,485,
  486,496,497,506,507,513,514,524,545,546,547,548,549,550,551,552,553,555,563,
  564,565,566,567,570,572,573,574,575,576,577,578,580,581,582,583,
  600,601,602,614,615,624,625,630,631,641,663,664,665,666,667,668,670,672,680,
  681,682,683,684,686,687,688,689,690,691,692,693,694,695,697,698,699,700,712,
  713,714,715,737,738,739,740,741,743,744,745,746,748,749,750,753,754,755,756,
  757,758,759,760,761,762,763,764,765,766,767,768,772,774,775,777
};
__device__ __constant__ int c_psplit[JSPLIT + 1] = {0, 13, 58, 131, 204};

__device__ inline float wave_sum(float v) {
  v += __shfl_down(v, 32);
  v += __shfl_down(v, 16);
  v += __shfl_down(v, 8);
  v += __shfl_down(v, 4);
  v += __shfl_down(v, 2);
  v += __shfl_down(v, 1);
  return v;
}

// pack candidate index into low 10 mantissa bits; float order ~ (t, j)
__device__ inline float packkey(float t, int j) {
  return __uint_as_float((__float_as_uint(t) & 0xFFFFFC00u) | (uint32)j);
}

// ======================= dispatch 1: mega1 =======================
// accs: 0 penetr,1 npts,2 contact,3 consist,4 loss_o,5 loss_h,6 recon_sq,7 kld,8 cnt
__global__ __launch_bounds__(256) void mega1a(
    const float* __restrict__ recon, const float* __restrict__ gt,
    const float* __restrict__ obj,
    float* __restrict__ keyR, float* __restrict__ keyG,
    float* __restrict__ priorK,
    float* __restrict__ minHR, float* __restrict__ minHG,
    float* __restrict__ accs)
{
  const int bid = blockIdx.x;
  const int tid = threadIdx.x;

  if (bid == 0 && tid < 16) accs[tid] = 0.0f;  // consumed after kernel boundary

  if (bid < OBJ_BLKS) {
    // ---- obj -> hand NN, j-split 4, + in-pass partial prior-NN ----
    __shared__ float4 shA[JCH];   // recon split
    __shared__ float4 shB[JCH];   // gt split
    const int b     = bid / (OBJ_TILES * JSPLIT);
    const int rem   = bid % (OBJ_TILES * JSPLIT);
    const int tile  = rem / JSPLIT;
    const int split = rem % JSPLIT;
    const int jbase = split * JCH;
    const int jcnt  = (NH - jbase < JCH) ? (NH - jbase) : JCH;

    for (int i = tid; i < jcnt; i += 256) {
      const float* p = recon + ((size_t)b * NH + jbase + i) * 3;
      float x = p[0], y = p[1], z = p[2];
      shA[i] = make_float4(x, y, z, x*x + y*y + z*z);
      const float* q = gt + ((size_t)b * NH + jbase + i) * 3;
      float gx = q[0], gy = q[1], gz = q[2];
      shB[i] = make_float4(gx, gy, gz, gx*gx + gy*gy + gz*gz);
    }
    __syncthreads();

    float nx[P_OBJ], ny[P_OBJ], nz[P_OBJ];
    int ob[P_OBJ]; bool val[P_OBJ];
    #pragma unroll
    for (int m = 0; m < P_OBJ; ++m) {
      int o = tile * OBJ_PTS + m * 256 + tid;
      ob[m] = o; val[m] = (o < NO);
      float x = 0.f, y = 0.f, z = 0.f;
      if (val[m]) {
        const float* op = obj + ((size_t)b * NO + o) * 3;
        x = op[0]; y = op[1]; z = op[2];
      }
      nx[m] = -2.f * x; ny[m] = -2.f * y; nz[m] = -2.f * z;
    }

    float bR[P_OBJ], bG[P_OBJ];
    #pragma unroll
    for (int m = 0; m < P_OBJ; ++m) { bR[m] = 3.4e38f; bG[m] = 3.4e38f; }

    int i = 0;
    for (; i + 1 < jcnt; i += 2) {
      float4 h0 = shA[i], h1 = shA[i + 1];
      #pragma unroll
      for (int m = 0; m < P_OBJ; ++m) {
        float t0 = fmaf(nx[m], h0.x, h0.w); t0 = fmaf(ny[m], h0.y, t0); t0 = fmaf(nz[m], h0.z, t0);
        float t1 = fmaf(nx[m], h1.x, h1.w); t1 = fmaf(ny[m], h1.y, t1); t1 = fmaf(nz[m], h1.z, t1);
        bR[m] = fminf(bR[m], fminf(packkey(t0, jbase + i), packkey(t1, jbase + i + 1)));
      }
      float4 g0 = shB[i], g1 = shB[i + 1];
      #pragma unroll
      for (int m = 0; m < P_OBJ; ++m) {
        float t0 = fmaf(nx[m], g0.x, g0.w); t0 = fmaf(ny[m], g0.y, t0); t0 = fmaf(nz[m], g0.z, t0);
        float t1 = fmaf(nx[m], g1.x, g1.w); t1 = fmaf(ny[m], g1.y, t1); t1 = fmaf(nz[m], g1.z, t1);
        bG[m] = fminf(bG[m], fminf(packkey(t0, jbase + i), packkey(t1, jbase + i + 1)));
      }
    }
    if (i < jcnt) {
      float4 h0 = shA[i];
      float4 g0 = shB[i];
      #pragma unroll
      for (int m = 0; m < P_OBJ; ++m) {
        float t0 = fmaf(nx[m], h0.x, h0.w); t0 = fmaf(ny[m], h0.y, t0); t0 = fmaf(nz[m], h0.z, t0);
        bR[m] = fminf(bR[m], packkey(t0, jbase + i));
        float u0 = fmaf(nx[m], g0.x, g0.w); u0 = fmaf(ny[m], g0.y, u0); u0 = fmaf(nz[m], g0.z, u0);
        bG[m] = fminf(bG[m], packkey(u0, jbase + i));
      }
    }

    // partial prior-NN over this split's prior members (recon candidates in shA)
    float bP[P_OBJ];
    #pragma unroll
    for (int m = 0; m < P_OBJ; ++m) bP[m] = 3.4e38f;
    const int pk0 = c_psplit[split], pk1 = c_psplit[split + 1];
    for (int k = pk0; k < pk1; ++k) {
      float4 h = shA[c_prior_sorted[k] - jbase];
      #pragma unroll
      for (int m = 0; m < P_OBJ; ++m) {
        float t = fmaf(nx[m], h.x, h.w);
        t = fmaf(ny[m], h.y, t);
        t = fmaf(nz[m], h.z, t);
        bP[m] = fminf(bP[m], t);
      }
    }

    #pragma unroll
    for (int m = 0; m < P_OBJ; ++m) {
      if (!val[m]) continue;
      const size_t idx = (size_t)split * NKEY + (size_t)b * NO + ob[m];
      keyR[idx] = bR[m];
      keyG[idx] = bG[m];
      priorK[idx] = bP[m];
    }
  } else {
    // ---- hand -> obj NN, 12 chunks, per-chunk t-min slices (R8-identical) ----
    __shared__ float4 sO[HCS];
    const int bid2 = bid - OBJ_BLKS;
    const int oc = bid2 % HC;
    const int b  = bid2 / HC;

    const float* Ob = obj + ((size_t)b * NO + oc * HCS) * 3;
    for (int i2 = tid; i2 < HCS; i2 += 256) {
      float x = Ob[3*i2], y = Ob[3*i2+1], z = Ob[3*i2+2];
      sO[i2] = make_float4(x, y, z, x*x + y*y + z*z);
    }
    __syncthreads();

    float nrx[4], nry[4], nrz[4];
    float ngx[4], ngy[4], ngz[4];
    bool val[4];
    #pragma unroll
    for (int m = 0; m < 4; ++m) {
      int j = m * 256 + tid;
      val[m] = (j < NH);
      float rx = 0.f, ry = 0.f, rz = 0.f, gx = 0.f, gy = 0.f, gz = 0.f;
      if (val[m]) {
        const float* rp = recon + ((size_t)b * NH + j) * 3;
        const float* gp = gt    + ((size_t)b * NH + j) * 3;
        rx = rp[0]; ry = rp[1]; rz = rp[2];
        gx = gp[0]; gy = gp[1]; gz = gp[2];
      }
      nrx[m] = -2.f*rx; nry[m] = -2.f*ry; nrz[m] = -2.f*rz;
      ngx[m] = -2.f*gx; ngy[m] = -2.f*gy; ngz[m] = -2.f*gz;
    }

    float mR[4], mG[4];
    #pragma unroll
    for (int m = 0; m < 4; ++m) { mR[m] = 3.4e38f; mG[m] = 3.4e38f; }

    for (int k = 0; k < HCS; k += 2) {
      float4 o0 = sO[k], o1 = sO[k + 1];
      #pragma unroll
      for (int m = 0; m < 4; ++m) {
        float t0 = fmaf(nrx[m], o0.x, o0.w); t0 = fmaf(nry[m], o0.y, t0); t0 = fmaf(nrz[m], o0.z, t0);
        float t1 = fmaf(nrx[m], o1.x, o1.w); t1 = fmaf(nry[m], o1.y, t1); t1 = fmaf(nrz[m], o1.z, t1);
        mR[m] = fminf(mR[m], fminf(t0, t1));
        float u0 = fmaf(ngx[m], o0.x, o0.w); u0 = fmaf(ngy[m], o0.y, u0); u0 = fmaf(ngz[m], o0.z, u0);
        float u1 = fmaf(ngx[m], o1.x, o1.w); u1 = fmaf(ngy[m], o1.y, u1); u1 = fmaf(ngz[m], o1.z, u1);
        mG[m] = fminf(mG[m], fminf(u0, u1));
      }
    }

    #pragma unroll
    for (int m = 0; m < 4; ++m) {
      if (!val[m]) continue;
      int j = m * 256 + tid;
      const size_t idx = (size_t)oc * NHT + (size_t)b * NH + j;
      minHR[idx] = mR[m];
      minHG[idx] = mG[m];
    }
  }
}

// ======================= dispatch 2: mega2 (R8-identical) =======================
__global__ __launch_bounds__(256) void mega2a(
    const float* __restrict__ recon, const float* __restrict__ gt,
    const float* __restrict__ rnorm, const float* __restrict__ gnorm,
    const float* __restrict__ obj,
    const float* __restrict__ mean, const float* __restrict__ logv,
    const float* __restrict__ vw,
    const float* __restrict__ keyR, const float* __restrict__ keyG,
    const float* __restrict__ priorK,
    const float* __restrict__ minHR, const float* __restrict__ minHG,
    float* __restrict__ accs, float* __restrict__ out)
{
  __shared__ float red[4][5];
  const int bid = blockIdx.x;
  const int tid = threadIdx.x;
  const int lane = tid & 63, wv = tid >> 6;

  if (bid < FIN_OBJ_BLKS) {
    const int b = bid / T2;
    const int tile = bid % T2;
    const int o = tile * 256 + tid;
    float penetr = 0.f, nptsv = 0.f, contactv = 0.f, consistv = 0.f, lossov = 0.f;
    if (o < NO) {
      const float* op = obj + ((size_t)b * NO + o) * 3;
      const float ox = op[0], oy = op[1], oz = op[2];
      const float o2 = ox*ox + oy*oy + oz*oz;
      const size_t base = (size_t)b * NO + o;

      float kR = 3.4e38f, kG = 3.4e38f, bP = 3.4e38f;
      #pragma unroll
      for (int s = 0; s < JSPLIT; ++s) {
        kR = fminf(kR, keyR[(size_t)s * NKEY + base]);
        kG = fminf(kG, keyG[(size_t)s * NKEY + base]);
        bP = fminf(bP, priorK[(size_t)s * NKEY + base]);
      }
      uint32 kRb = __float_as_uint(kR), kGb = __float_as_uint(kG);
      int idxR = (int)(kRb & 0x3FFu), idxG = (int)(kGb & 0x3FFu);
      float d2R = fmaxf(__uint_as_float(kRb & 0xFFFFFC00u) + o2, 0.f);
      float d2G = fmaxf(__uint_as_float(kGb & 0xFFFFFC00u) + o2, 0.f);
      float d2P = fmaxf(bP + o2, 0.f);

      const float* hR = recon + ((size_t)b * NH + idxR) * 3;
      const float* nR = rnorm + ((size_t)b * NH + idxR) * 3;
      float dotR = (ox - hR[0]) * nR[0] + (oy - hR[1]) * nR[1] + (oz - hR[2]) * nR[2];
      const float* hG = gt + ((size_t)b * NH + idxG) * 3;
      const float* nG = gnorm + ((size_t)b * NH + idxG) * 3;
      float dotG = (ox - hG[0]) * nG[0] + (oy - hG[1]) * nG[1] + (oz - hG[2]) * nG[2];

      float sgnR = (dotR > 0.f) ? 1.f : ((dotR < 0.f) ? -1.f : 0.f);
      float sgnG = (dotG > 0.f) ? 1.f : ((dotG < 0.f) ? -1.f : 0.f);
      float sR_ = sqrtf(d2R), sG_ = sqrtf(d2G);
      float o2h = sR_ * sgnR, o2hg = sG_ * sgnG;

      bool interior = dotR < 0.f;
      bool cmap = sG_ < 0.005f;
      bool rcmap = sR_ < 0.005f;

      penetr   = interior ? d2R : 0.f;
      nptsv    = cmap ? 1.f : 0.f;
      contactv = cmap ? d2P : 0.f;
      consistv = (cmap && rcmap) ? 1.f : 0.f;
      float w = (o2h < 0.f) ? 1.5f
              : (((o2hg < 0.01f) && (o2hg > -0.005f)) ? 1.f : 0.1f);
      lossov = fabsf(o2h - o2hg) * w;
    }

    float vals[5] = {penetr, nptsv, contactv, consistv, lossov};
    #pragma unroll
    for (int q = 0; q < 5; ++q) {
      float s = wave_sum(vals[q]);
      if (lane == 0) red[wv][q] = s;
    }
    __syncthreads();
    if (tid < 5) {
      float s = red[0][tid] + red[1][tid] + red[2][tid] + red[3][tid];
      atomicAdd(&accs[tid], s);
    }
  } else {
    const int t = (bid - FIN_OBJ_BLKS) * 256 + tid;
    float lossh = 0.f, rsum = 0.f, ksum = 0.f;
    if (t < NB * NH) {
      const float* rp = recon + (size_t)t * 3;
      const float* gp = gt + (size_t)t * 3;
      float rx = rp[0], ry = rp[1], rz = rp[2];
      float gx = gp[0], gy = gp[1], gz = gp[2];
      float d0 = rx - gx, d1 = ry - gy, d2 = rz - gz;
      rsum = d0*d0 + d1*d1 + d2*d2;

      float tR[HC], tG[HC];
      #pragma unroll
      for (int c = 0; c < HC; ++c) {
        tR[c] = minHR[(size_t)c * NHT + t];
        tG[c] = minHG[(size_t)c * NHT + t];
      }
      float mRt = tR[0], mGt = tG[0];
      #pragma unroll
      for (int c = 1; c < HC; ++c) {
        mRt = fminf(mRt, tR[c]);
        mGt = fminf(mGt, tG[c]);
      }
      float r2 = rx*rx + ry*ry + rz*rz;
      float g2 = gx*gx + gy*gy + gz*gz;
      float d2Rh = fmaxf(mRt + r2, 0.f);
      float d2Gh = fmaxf(mGt + g2, 0.f);
      int j = t % NH;
      lossh = fabsf(sqrtf(d2Rh) - sqrtf(d2Gh)) * powf(vw[j], 0.4f);
    }
    if (t < NB * NZ) {
      float m = mean[t], lv = logv[t];
      ksum = 1.f + lv - m * m - expf(lv);
    }
    float vals[3] = {lossh, rsum, ksum};
    #pragma unroll
    for (int q = 0; q < 3; ++q) {
      float s = wave_sum(vals[q]);
      if (lane == 0) red[wv][q] = s;
    }
    __syncthreads();
    if (tid < 3) {
      float s = red[0][tid] + red[1][tid] + red[2][tid] + red[3][tid];
      atomicAdd(&accs[5 + tid], s);
    }
  }

  __syncthreads();
  if (tid == 0) {
    __threadfence();
    int* cnt = (int*)(accs + 8);
    int old = atomicAdd(cnt, 1);
    if (old == FIN_BLKS - 1) {
      float a[8];
      #pragma unroll
      for (int q = 0; q < 8; ++q) a[q] = atomicAdd(&accs[q], 0.0f);
      const float recon_loss = a[6] / (float)NB;
      const float kld = -0.5f * a[7] / (float)NB * 10.f;
      const float penetr = 100.f * a[0] / (float)NB;
      const float npts = a[1];
      const float contact = (npts > 0.f) ? (3000.f * a[2] / ((float)NB * npts)) : 0.f;
      const float consistency = -5.f * a[3] / (npts + 0.0001f);
      const float lossh = 35.f * (1.f - 0.005f) * (a[5] / (float)(NB * NH));
      const float losso = 30.f * (1.f - 0.005f) * (a[4] / (float)(NB * NO));
      out[0] = recon_loss + 0.1f * kld + 1000.f * penetr + 10.f * contact
             + 10.f * consistency + lossh + losso;
    }
  }
}

// =========================== PATH C (tiny ws fallback) ===========================
__global__ __launch_bounds__(256) void obj_mono(
    const float* __restrict__ recon, const float* __restrict__ gt,
    const float* __restrict__ rnorm, const float* __restrict__ gnorm,
    const float* __restrict__ obj, float* __restrict__ accs)
{
  __shared__ float4 sR[NH];
  __shared__ float4 sG[NH];
  __shared__ float red[4][5];
  const int b = blockIdx.x / 12;
  const int tile = blockIdx.x % 12;
  const int tid = threadIdx.x;
  for (int i = tid; i < NH; i += 256) {
    const float* p = recon + ((size_t)b * NH + i) * 3;
    float x = p[0], y = p[1], z = p[2];
    sR[i] = make_float4(x, y, z, x*x + y*y + z*z);
    const float* q = gt + ((size_t)b * NH + i) * 3;
    float gx = q[0], gy = q[1], gz = q[2];
    sG[i] = make_float4(gx, gy, gz, gx*gx + gy*gy + gz*gz);
  }
  __syncthreads();
  const int o = tile * 256 + tid;
  float penetr = 0.f, nptsv = 0.f, contactv = 0.f, consistv = 0.f, lossov = 0.f;
  if (o < NO) {
    const float* op = obj + ((size_t)b * NO + o) * 3;
    const float ox = op[0], oy = op[1], oz = op[2];
    const float nx = -2.f*ox, ny = -2.f*oy, nz = -2.f*oz;
    const float o2 = ox*ox + oy*oy + oz*oz;
    float bR = 3.4e38f, bG = 3.4e38f; int iR = 0, iG = 0;
    for (int i = 0; i < NH; ++i) {
      float4 h = sR[i];
      float t = fmaf(nx, h.x, h.w); t = fmaf(ny, h.y, t); t = fmaf(nz, h.z, t);
      if (t < bR) { bR = t; iR = i; }
      float4 g = sG[i];
      float u = fmaf(nx, g.x, g.w); u = fmaf(ny, g.y, u); u = fmaf(nz, g.z, u);
      if (u < bG) { bG = u; iG = i; }
    }
    float bP = 3.4e38f;
    for (int k = 0; k < NP; ++k) {
      float4 h = sR[c_prior[k]];
      float t = fmaf(nx, h.x, h.w); t = fmaf(ny, h.y, t); t = fmaf(nz, h.z, t);
      bP = fminf(bP, t);
    }
    float d2R = fmaxf(bR + o2, 0.f);
    float d2G = fmaxf(bG + o2, 0.f);
    float d2P = fmaxf(bP + o2, 0.f);
    float4 hR = sR[iR];
    const float* nR = rnorm + ((size_t)b * NH + iR) * 3;
    float dotR = (ox-hR.x)*nR[0] + (oy-hR.y)*nR[1] + (oz-hR.z)*nR[2];
    float4 hG = sG[iG];
    const float* nG = gnorm + ((size_t)b * NH + iG) * 3;
    float dotG = (ox-hG.x)*nG[0] + (oy-hG.y)*nG[1] + (oz-hG.z)*nG[2];
    float sgnR = (dotR > 0.f) ? 1.f : ((dotR < 0.f) ? -1.f : 0.f);
    float sgnG = (dotG > 0.f) ? 1.f : ((dotG < 0.f) ? -1.f : 0.f);
    float sR_ = sqrtf(d2R), sG_ = sqrtf(d2G);
    float o2h = sR_*sgnR, o2hg = sG_*sgnG;
    bool interior = dotR < 0.f;
    bool cmap = sG_ < 0.005f, rcmap = sR_ < 0.005f;
    penetr = interior ? d2R : 0.f;
    nptsv = cmap ? 1.f : 0.f;
    contactv = cmap ? d2P : 0.f;
    consistv = (cmap && rcmap) ? 1.f : 0.f;
    float w = (o2h < 0.f) ? 1.5f : (((o2hg < 0.01f) && (o2hg > -0.005f)) ? 1.f : 0.1f);
    lossov = fabsf(o2h - o2hg) * w;
  }
  float vals[5] = {penetr, nptsv, contactv, consistv, lossov};
  const int lane = tid & 63, wv = tid >> 6;
  for (int q = 0; q < 5; ++q) {
    float s = wave_sum(vals[q]);
    if (lane == 0) red[wv][q] = s;
  }
  __syncthreads();
  if (tid < 5) {
    float s = red[0][tid] + red[1][tid] + red[2][tid] + red[3][tid];
    atomicAdd(&accs[tid], s);
  }
}

__global__ __launch_bounds__(256) void hand_full(
    const float* __restrict__ recon, const float* __restrict__ gt,
    const float* __restrict__ obj, const float* __restrict__ vw,
    float* __restrict__ accs)
{
  __shared__ float4 sO[500];
  __shared__ float red[4];
  const int b = blockIdx.x >> 2;
  const int j = ((blockIdx.x & 3) << 8) + threadIdx.x;
  const bool valid = j < NH;
  float rx=0,ry=0,rz=0,gx=0,gy=0,gz=0;
  if (valid) {
    const float* rp = recon + ((size_t)b * NH + j) * 3;
    const float* gp = gt + ((size_t)b * NH + j) * 3;
    rx=rp[0];ry=rp[1];rz=rp[2]; gx=gp[0];gy=gp[1];gz=gp[2];
  }
  const float nrx=-2.f*rx, nry=-2.f*ry, nrz=-2.f*rz;
  const float ngx=-2.f*gx, ngy=-2.f*gy, ngz=-2.f*gz;
  const float r2 = rx*rx+ry*ry+rz*rz, g2 = gx*gx+gy*gy+gz*gz;
  float mR = 3.4e38f, mG = 3.4e38f;
  for (int oc = 0; oc < 6; ++oc) {
    __syncthreads();
    const float* Ob = obj + ((size_t)b * NO + oc * 500) * 3;
    for (int i = threadIdx.x; i < 500; i += 256) {
      float x = Ob[3*i], y = Ob[3*i+1], z = Ob[3*i+2];
      sO[i] = make_float4(x, y, z, x*x + y*y + z*z);
    }
    __syncthreads();
    if (valid) {
      for (int k = 0; k < 500; ++k) {
        float4 o4 = sO[k];
        float t = fmaf(nrx,o4.x,o4.w); t = fmaf(nry,o4.y,t); t = fmaf(nrz,o4.z,t);
        mR = fminf(mR, t);
        float u = fmaf(ngx,o4.x,o4.w); u = fmaf(ngy,o4.y,u); u = fmaf(ngz,o4.z,u);
        mG = fminf(mG, u);
      }
    }
  }
  float lossh = valid ? fabsf(sqrtf(fmaxf(mR+r2,0.f)) - sqrtf(fmaxf(mG+g2,0.f))) * powf(vw[j], 0.4f) : 0.f;
  const int lane = threadIdx.x & 63, wv = threadIdx.x >> 6;
  float s = wave_sum(lossh);
  if (lane == 0) red[wv] = s;
  __syncthreads();
  if (threadIdx.x == 0) atomicAdd(&accs[5], red[0]+red[1]+red[2]+red[3]);
}

__global__ __launch_bounds__(256) void tail_nomins(
    const float* __restrict__ recon, const float* __restrict__ gt,
    const float* __restrict__ mean, const float* __restrict__ logv,
    float* __restrict__ accs)
{
  __shared__ float red[4][2];
  const int t = blockIdx.x * 256 + threadIdx.x;
  float rsum = 0.f, ksum = 0.f;
  if (t < NB * NH) {
    const float* rp = recon + (size_t)t * 3;
    const float* gp = gt + (size_t)t * 3;
    float d0 = rp[0]-gp[0], d1 = rp[1]-gp[1], d2 = rp[2]-gp[2];
    rsum = d0*d0 + d1*d1 + d2*d2;
  }
  if (t < NB * NZ) {
    float m = mean[t], lv = logv[t];
    ksum = 1.f + lv - m*m - expf(lv);
  }
  float vals[2] = {rsum, ksum};
  const int lane = threadIdx.x & 63, wv = threadIdx.x >> 6;
  for (int q = 0; q < 2; ++q) {
    float s = wave_sum(vals[q]);
    if (lane == 0) red[wv][q] = s;
  }
  __syncthreads();
  if (threadIdx.x < 2) {
    float s = red[0][threadIdx.x] + red[1][threadIdx.x] + red[2][threadIdx.x] + red[3][threadIdx.x];
    atomicAdd(&accs[6 + threadIdx.x], s);
  }
}

__global__ void init_small(float* accs) {
  int t = threadIdx.x;
  if (t < 8) accs[t] = 0.0f;
}

__global__ void final_fb(const float* __restrict__ a, float* __restrict__ out) {
  const float recon_loss = a[6] / (float)NB;
  const float kld = -0.5f * a[7] / (float)NB * 10.f;
  const float penetr = 100.f * a[0] / (float)NB;
  const float npts = a[1];
  const float contact = (npts > 0.f) ? (3000.f * a[2] / ((float)NB * npts)) : 0.f;
  const float consistency = -5.f * a[3] / (npts + 0.0001f);
  const float lossh = 35.f * (1.f - 0.005f) * (a[5] / (float)(NB * NH));
  const float losso = 30.f * (1.f - 0.005f) * (a[4] / (float)(NB * NO));
  out[0] = recon_loss + 0.1f*kld + 1000.f*penetr + 10.f*contact + 10.f*consistency + lossh + losso;
}

extern "C" void kernel_launch(void* const* d_in, const int* in_sizes, int n_in,
                              void* d_out, int out_size, void* d_ws, size_t ws_size,
                              hipStream_t stream) {
  const float* recon = (const float*)d_in[0];
  const float* gt    = (const float*)d_in[1];
  const float* rnorm = (const float*)d_in[2];
  const float* gnorm = (const float*)d_in[3];
  const float* obj   = (const float*)d_in[4];
  const float* mean  = (const float*)d_in[5];
  const float* logv  = (const float*)d_in[6];
  const float* vw    = (const float*)d_in[7];
  float* out = (float*)d_out;

  // ws: accs[16] @0 | slices @256: keyR[4N] keyG[4N] priorK[4N] minHR[12H] minHG[12H]
  float* accs   = (float*)d_ws;
  float* keyR   = (float*)((char*)d_ws + 256);
  float* keyG   = keyR + (size_t)JSPLIT * NKEY;
  float* priorK = keyG + (size_t)JSPLIT * NKEY;
  float* minHR  = priorK + (size_t)JSPLIT * NKEY;
  float* minHG  = minHR + (size_t)HC * NHT;
  const size_t neededA = 256 + (3ull * JSPLIT * NKEY + 2ull * HC * NHT) * sizeof(float);

  if (ws_size >= neededA) {
    mega1a<<<OBJ_BLKS + HAND_BLKS, 256, 0, stream>>>(
        recon, gt, obj, keyR, keyG, priorK, minHR, minHG, accs);
    mega2a<<<FIN_BLKS, 256, 0, stream>>>(
        recon, gt, rnorm, gnorm, obj, mean, logv, vw,
        keyR, keyG, priorK, minHR, minHG, accs, out);
  } else {
    init_small<<<1, 64, 0, stream>>>(accs);
    obj_mono<<<NB * 12, 256, 0, stream>>>(recon, gt, rnorm, gnorm, obj, accs);
    hand_full<<<NB * 4, 256, 0, stream>>>(recon, gt, obj, vw, accs);
    tail_nomins<<<(NB * NH + 255) / 256, 256, 0, stream>>>(recon, gt, mean, logv, accs);
    final_fb<<<1, 1, 0, stream>>>(accs, out);
  }
}

// Round 12
// 121.295 us; speedup vs baseline: 1.0680x; 1.0542x over previous
//
#include <hip/hip_runtime.h>
#include <math.h>

// GraspCVAE loss, MI355X — round 12: exact revert to round 8 (best verified:
// 121.26us, mega1a 42.2us @ VALUBusy 99.98%, absmax 0.0).
// R10 (packed fp16) and R11 (P_OBJ=6) both regressed mega1 — the R8
// configuration is issue-saturated and both "instruction diet" variants lost
// more to scheduling/occupancy than they gained. Restoring R8 verbatim.
//   mega1 (768 blks): obj->hand NN (j-split 4, packed-index keys) + in-pass
//     partial prior-NN (sorted prior list, per-split offsets); hand->obj NN
//     (12 chunks). Plain stores to disjoint ws slices. Block 0 zeroes accs.
//   mega2 (482 blks): slice-reduce + epilogue + fused final combine.

#define NB 32
#define NH 778
#define NO 3000
#define NZ 64
#define NP 204

#define P_OBJ 4
#define OBJ_PTS 1024
#define OBJ_TILES 3                   // ceil(3000/1024)
#define JSPLIT 4
#define JCH 195                       // ceil(778/4)
#define HC 12                         // hand-side obj chunks
#define HCS 250                       // 3000/12
#define OBJ_BLKS (NB * OBJ_TILES * JSPLIT)    // 384
#define HAND_BLKS (NB * HC)                   // 384
#define T2 12                         // mega2 obj tiles (256 pts)
#define FIN_OBJ_BLKS (NB * T2)                // 384
#define FIN_TAIL_BLKS ((NB * NH + 255) / 256) // 98
#define FIN_BLKS (FIN_OBJ_BLKS + FIN_TAIL_BLKS) // 482

#define NKEY (NB * NO)                // 96000
#define NHT  (NB * NH)                // 24896

typedef unsigned int uint32;

// original order (PATH C)
__device__ __constant__ int c_prior[NP] = {
  697,698,699,700,712,713,714,715,737,738,739,740,741,743,744,745,746,748,749,750,
  753,754,755,756,757,758,759,760,761,762,763,764,765,766,767,768,
  46,47,48,49,164,165,166,167,194,195,223,237,238,280,281,298,301,317,320,323,
  324,325,326,327,328,329,330,331,332,333,340,341,342,343,344,345,346,347,348,349,
  350,351,352,353,354,355,
  356,357,358,359,375,376,386,387,396,397,402,403,413,429,433,434,435,436,437,438,
  439,440,441,442,443,444,452,453,454,455,456,459,460,461,462,463,464,465,466,467,
  468,469,470,471,484,485,486,496,497,506,507,513,514,524,545,546,547,548,549,550,
  551,552,553,555,563,564,565,566,567,570,572,573,574,575,576,577,578,
  580,581,582,583,600,601,602,614,615,624,625,630,631,641,663,664,665,666,667,668,
  670,672,680,681,682,683,684,686,687,688,689,690,691,692,693,694,695,
  73,96,98,99,772,774,775,777
};

// sorted ascending; per-JCH-split offsets: [0,13) [13,58) [58,131) [131,204)
__device__ __constant__ int c_prior_sorted[NP] = {
  46,47,48,49,73,96,98,99,164,165,166,167,194,
  195,223,237,238,280,281,298,301,317,320,323,324,325,326,327,328,329,330,331,
  332,333,340,341,342,343,344,345,346,347,348,349,350,351,352,353,354,355,356,
  357,358,359,375,376,386,387,
  396,397,402,403,413,429,433,434,435,436,437,438,439,440,441,442,443,444,452,
  453,454,455,456,459,460,461,462,463,464,465,466,467,468,469,470,471,484,485,
  486,496,497,506,507,513,514,524,545,546,547,548,549,550,551,552,553,555,563,
  564,565,566,567,570,572,573,574,575,576,577,578,580,581,582,583,
  600,601,602,614,615,624,625,630,631,641,663,664,665,666,667,668,670,672,680,
  681,682,683,684,686,687,688,689,690,691,692,693,694,695,697,698,699,700,712,
  713,714,715,737,738,739,740,741,743,744,745,746,748,749,750,753,754,755,756,
  757,758,759,760,761,762,763,764,765,766,767,768,772,774,775,777
};
__device__ __constant__ int c_psplit[JSPLIT + 1] = {0, 13, 58, 131, 204};

__device__ inline float wave_sum(float v) {
  v += __shfl_down(v, 32);
  v += __shfl_down(v, 16);
  v += __shfl_down(v, 8);
  v += __shfl_down(v, 4);
  v += __shfl_down(v, 2);
  v += __shfl_down(v, 1);
  return v;
}

// pack candidate index into low 10 mantissa bits; float order ~ (t, j)
__device__ inline float packkey(float t, int j) {
  return __uint_as_float((__float_as_uint(t) & 0xFFFFFC00u) | (uint32)j);
}

// ======================= dispatch 1: mega1 =======================
// accs: 0 penetr,1 npts,2 contact,3 consist,4 loss_o,5 loss_h,6 recon_sq,7 kld,8 cnt
__global__ __launch_bounds__(256) void mega1a(
    const float* __restrict__ recon, const float* __restrict__ gt,
    const float* __restrict__ obj,
    float* __restrict__ keyR, float* __restrict__ keyG,
    float* __restrict__ priorK,
    float* __restrict__ minHR, float* __restrict__ minHG,
    float* __restrict__ accs)
{
  const int bid = blockIdx.x;
  const int tid = threadIdx.x;

  if (bid == 0 && tid < 16) accs[tid] = 0.0f;  // consumed after kernel boundary

  if (bid < OBJ_BLKS) {
    // ---- obj -> hand NN, j-split 4, + in-pass partial prior-NN ----
    __shared__ float4 shA[JCH];   // recon split
    __shared__ float4 shB[JCH];   // gt split
    const int b     = bid / (OBJ_TILES * JSPLIT);
    const int rem   = bid % (OBJ_TILES * JSPLIT);
    const int tile  = rem / JSPLIT;
    const int split = rem % JSPLIT;
    const int jbase = split * JCH;
    const int jcnt  = (NH - jbase < JCH) ? (NH - jbase) : JCH;

    for (int i = tid; i < jcnt; i += 256) {
      const float* p = recon + ((size_t)b * NH + jbase + i) * 3;
      float x = p[0], y = p[1], z = p[2];
      shA[i] = make_float4(x, y, z, x*x + y*y + z*z);
      const float* q = gt + ((size_t)b * NH + jbase + i) * 3;
      float gx = q[0], gy = q[1], gz = q[2];
      shB[i] = make_float4(gx, gy, gz, gx*gx + gy*gy + gz*gz);
    }
    __syncthreads();

    float nx[P_OBJ], ny[P_OBJ], nz[P_OBJ];
    int ob[P_OBJ]; bool val[P_OBJ];
    #pragma unroll
    for (int m = 0; m < P_OBJ; ++m) {
      int o = tile * OBJ_PTS + m * 256 + tid;
      ob[m] = o; val[m] = (o < NO);
      float x = 0.f, y = 0.f, z = 0.f;
      if (val[m]) {
        const float* op = obj + ((size_t)b * NO + o) * 3;
        x = op[0]; y = op[1]; z = op[2];
      }
      nx[m] = -2.f * x; ny[m] = -2.f * y; nz[m] = -2.f * z;
    }

    float bR[P_OBJ], bG[P_OBJ];
    #pragma unroll
    for (int m = 0; m < P_OBJ; ++m) { bR[m] = 3.4e38f; bG[m] = 3.4e38f; }

    int i = 0;
    for (; i + 1 < jcnt; i += 2) {
      float4 h0 = shA[i], h1 = shA[i + 1];
      #pragma unroll
      for (int m = 0; m < P_OBJ; ++m) {
        float t0 = fmaf(nx[m], h0.x, h0.w); t0 = fmaf(ny[m], h0.y, t0); t0 = fmaf(nz[m], h0.z, t0);
        float t1 = fmaf(nx[m], h1.x, h1.w); t1 = fmaf(ny[m], h1.y, t1); t1 = fmaf(nz[m], h1.z, t1);
        bR[m] = fminf(bR[m], fminf(packkey(t0, jbase + i), packkey(t1, jbase + i + 1)));
      }
      float4 g0 = shB[i], g1 = shB[i + 1];
      #pragma unroll
      for (int m = 0; m < P_OBJ; ++m) {
        float t0 = fmaf(nx[m], g0.x, g0.w); t0 = fmaf(ny[m], g0.y, t0); t0 = fmaf(nz[m], g0.z, t0);
        float t1 = fmaf(nx[m], g1.x, g1.w); t1 = fmaf(ny[m], g1.y, t1); t1 = fmaf(nz[m], g1.z, t1);
        bG[m] = fminf(bG[m], fminf(packkey(t0, jbase + i), packkey(t1, jbase + i + 1)));
      }
    }
    if (i < jcnt) {
      float4 h0 = shA[i];
      float4 g0 = shB[i];
      #pragma unroll
      for (int m = 0; m < P_OBJ; ++m) {
        float t0 = fmaf(nx[m], h0.x, h0.w); t0 = fmaf(ny[m], h0.y, t0); t0 = fmaf(nz[m], h0.z, t0);
        bR[m] = fminf(bR[m], packkey(t0, jbase + i));
        float u0 = fmaf(nx[m], g0.x, g0.w); u0 = fmaf(ny[m], g0.y, u0); u0 = fmaf(nz[m], g0.z, u0);
        bG[m] = fminf(bG[m], packkey(u0, jbase + i));
      }
    }

    // partial prior-NN over this split's prior members (recon candidates in shA)
    float bP[P_OBJ];
    #pragma unroll
    for (int m = 0; m < P_OBJ; ++m) bP[m] = 3.4e38f;
    const int pk0 = c_psplit[split], pk1 = c_psplit[split + 1];
    for (int k = pk0; k < pk1; ++k) {
      float4 h = shA[c_prior_sorted[k] - jbase];
      #pragma unroll
      for (int m = 0; m < P_OBJ; ++m) {
        float t = fmaf(nx[m], h.x, h.w);
        t = fmaf(ny[m], h.y, t);
        t = fmaf(nz[m], h.z, t);
        bP[m] = fminf(bP[m], t);
      }
    }

    #pragma unroll
    for (int m = 0; m < P_OBJ; ++m) {
      if (!val[m]) continue;
      const size_t idx = (size_t)split * NKEY + (size_t)b * NO + ob[m];
      keyR[idx] = bR[m];
      keyG[idx] = bG[m];
      priorK[idx] = bP[m];
    }
  } else {
    // ---- hand -> obj NN, 12 chunks, per-chunk t-min slices ----
    __shared__ float4 sO[HCS];
    const int bid2 = bid - OBJ_BLKS;
    const int oc = bid2 % HC;
    const int b  = bid2 / HC;

    const float* Ob = obj + ((size_t)b * NO + oc * HCS) * 3;
    for (int i2 = tid; i2 < HCS; i2 += 256) {
      float x = Ob[3*i2], y = Ob[3*i2+1], z = Ob[3*i2+2];
      sO[i2] = make_float4(x, y, z, x*x + y*y + z*z);
    }
    __syncthreads();

    float nrx[4], nry[4], nrz[4];
    float ngx[4], ngy[4], ngz[4];
    bool val[4];
    #pragma unroll
    for (int m = 0; m < 4; ++m) {
      int j = m * 256 + tid;
      val[m] = (j < NH);
      float rx = 0.f, ry = 0.f, rz = 0.f, gx = 0.f, gy = 0.f, gz = 0.f;
      if (val[m]) {
        const float* rp = recon + ((size_t)b * NH + j) * 3;
        const float* gp = gt    + ((size_t)b * NH + j) * 3;
        rx = rp[0]; ry = rp[1]; rz = rp[2];
        gx = gp[0]; gy = gp[1]; gz = gp[2];
      }
      nrx[m] = -2.f*rx; nry[m] = -2.f*ry; nrz[m] = -2.f*rz;
      ngx[m] = -2.f*gx; ngy[m] = -2.f*gy; ngz[m] = -2.f*gz;
    }

    float mR[4], mG[4];
    #pragma unroll
    for (int m = 0; m < 4; ++m) { mR[m] = 3.4e38f; mG[m] = 3.4e38f; }

    for (int k = 0; k < HCS; k += 2) {
      float4 o0 = sO[k], o1 = sO[k + 1];
      #pragma unroll
      for (int m = 0; m < 4; ++m) {
        float t0 = fmaf(nrx[m], o0.x, o0.w); t0 = fmaf(nry[m], o0.y, t0); t0 = fmaf(nrz[m], o0.z, t0);
        float t1 = fmaf(nrx[m], o1.x, o1.w); t1 = fmaf(nry[m], o1.y, t1); t1 = fmaf(nrz[m], o1.z, t1);
        mR[m] = fminf(mR[m], fminf(t0, t1));
        float u0 = fmaf(ngx[m], o0.x, o0.w); u0 = fmaf(ngy[m], o0.y, u0); u0 = fmaf(ngz[m], o0.z, u0);
        float u1 = fmaf(ngx[m], o1.x, o1.w); u1 = fmaf(ngy[m], o1.y, u1); u1 = fmaf(ngz[m], o1.z, u1);
        mG[m] = fminf(mG[m], fminf(u0, u1));
      }
    }

    #pragma unroll
    for (int m = 0; m < 4; ++m) {
      if (!val[m]) continue;
      int j = m * 256 + tid;
      const size_t idx = (size_t)oc * NHT + (size_t)b * NH + j;
      minHR[idx] = mR[m];
      minHG[idx] = mG[m];
    }
  }
}

// ======================= dispatch 2: mega2 =======================
__global__ __launch_bounds__(256) void mega2a(
    const float* __restrict__ recon, const float* __restrict__ gt,
    const float* __restrict__ rnorm, const float* __restrict__ gnorm,
    const float* __restrict__ obj,
    const float* __restrict__ mean, const float* __restrict__ logv,
    const float* __restrict__ vw,
    const float* __restrict__ keyR, const float* __restrict__ keyG,
    const float* __restrict__ priorK,
    const float* __restrict__ minHR, const float* __restrict__ minHG,
    float* __restrict__ accs, float* __restrict__ out)
{
  __shared__ float red[4][5];
  const int bid = blockIdx.x;
  const int tid = threadIdx.x;
  const int lane = tid & 63, wv = tid >> 6;

  if (bid < FIN_OBJ_BLKS) {
    // ---- obj finalize: 12 slice loads + 2 gathers + epilogue (no staging) ----
    const int b = bid / T2;
    const int tile = bid % T2;
    const int o = tile * 256 + tid;
    float penetr = 0.f, nptsv = 0.f, contactv = 0.f, consistv = 0.f, lossov = 0.f;
    if (o < NO) {
      const float* op = obj + ((size_t)b * NO + o) * 3;
      const float ox = op[0], oy = op[1], oz = op[2];
      const float o2 = ox*ox + oy*oy + oz*oz;
      const size_t base = (size_t)b * NO + o;

      float kR = 3.4e38f, kG = 3.4e38f, bP = 3.4e38f;
      #pragma unroll
      for (int s = 0; s < JSPLIT; ++s) {
        kR = fminf(kR, keyR[(size_t)s * NKEY + base]);
        kG = fminf(kG, keyG[(size_t)s * NKEY + base]);
        bP = fminf(bP, priorK[(size_t)s * NKEY + base]);
      }
      uint32 kRb = __float_as_uint(kR), kGb = __float_as_uint(kG);
      int idxR = (int)(kRb & 0x3FFu), idxG = (int)(kGb & 0x3FFu);
      float d2R = fmaxf(__uint_as_float(kRb & 0xFFFFFC00u) + o2, 0.f);
      float d2G = fmaxf(__uint_as_float(kGb & 0xFFFFFC00u) + o2, 0.f);
      float d2P = fmaxf(bP + o2, 0.f);

      const float* hR = recon + ((size_t)b * NH + idxR) * 3;
      const float* nR = rnorm + ((size_t)b * NH + idxR) * 3;
      float dotR = (ox - hR[0]) * nR[0] + (oy - hR[1]) * nR[1] + (oz - hR[2]) * nR[2];
      const float* hG = gt + ((size_t)b * NH + idxG) * 3;
      const float* nG = gnorm + ((size_t)b * NH + idxG) * 3;
      float dotG = (ox - hG[0]) * nG[0] + (oy - hG[1]) * nG[1] + (oz - hG[2]) * nG[2];

      float sgnR = (dotR > 0.f) ? 1.f : ((dotR < 0.f) ? -1.f : 0.f);
      float sgnG = (dotG > 0.f) ? 1.f : ((dotG < 0.f) ? -1.f : 0.f);
      float sR_ = sqrtf(d2R), sG_ = sqrtf(d2G);
      float o2h = sR_ * sgnR, o2hg = sG_ * sgnG;

      bool interior = dotR < 0.f;
      bool cmap = sG_ < 0.005f;
      bool rcmap = sR_ < 0.005f;

      penetr   = interior ? d2R : 0.f;
      nptsv    = cmap ? 1.f : 0.f;
      contactv = cmap ? d2P : 0.f;
      consistv = (cmap && rcmap) ? 1.f : 0.f;
      float w = (o2h < 0.f) ? 1.5f
              : (((o2hg < 0.01f) && (o2hg > -0.005f)) ? 1.f : 0.1f);
      lossov = fabsf(o2h - o2hg) * w;
    }

    float vals[5] = {penetr, nptsv, contactv, consistv, lossov};
    #pragma unroll
    for (int q = 0; q < 5; ++q) {
      float s = wave_sum(vals[q]);
      if (lane == 0) red[wv][q] = s;
    }
    __syncthreads();
    if (tid < 5) {
      float s = red[0][tid] + red[1][tid] + red[2][tid] + red[3][tid];
      atomicAdd(&accs[tid], s);
    }
  } else {
    // ---- tail: reduce hand-chunk mins, loss_h, recon_loss, KLD ----
    const int t = (bid - FIN_OBJ_BLKS) * 256 + tid;
    float lossh = 0.f, rsum = 0.f, ksum = 0.f;
    if (t < NB * NH) {
      const float* rp = recon + (size_t)t * 3;
      const float* gp = gt + (size_t)t * 3;
      float rx = rp[0], ry = rp[1], rz = rp[2];
      float gx = gp[0], gy = gp[1], gz = gp[2];
      float d0 = rx - gx, d1 = ry - gy, d2 = rz - gz;
      rsum = d0*d0 + d1*d1 + d2*d2;

      float tR[HC], tG[HC];
      #pragma unroll
      for (int c = 0; c < HC; ++c) {
        tR[c] = minHR[(size_t)c * NHT + t];
        tG[c] = minHG[(size_t)c * NHT + t];
      }
      float mRt = tR[0], mGt = tG[0];
      #pragma unroll
      for (int c = 1; c < HC; ++c) {
        mRt = fminf(mRt, tR[c]);
        mGt = fminf(mGt, tG[c]);
      }
      float r2 = rx*rx + ry*ry + rz*rz;
      float g2 = gx*gx + gy*gy + gz*gz;
      float d2Rh = fmaxf(mRt + r2, 0.f);
      float d2Gh = fmaxf(mGt + g2, 0.f);
      int j = t % NH;
      lossh = fabsf(sqrtf(d2Rh) - sqrtf(d2Gh)) * powf(vw[j], 0.4f);
    }
    if (t < NB * NZ) {
      float m = mean[t], lv = logv[t];
      ksum = 1.f + lv - m * m - expf(lv);
    }
    float vals[3] = {lossh, rsum, ksum};
    #pragma unroll
    for (int q = 0; q < 3; ++q) {
      float s = wave_sum(vals[q]);
      if (lane == 0) red[wv][q] = s;
    }
    __syncthreads();
    if (tid < 3) {
      float s = red[0][tid] + red[1][tid] + red[2][tid] + red[3][tid];
      atomicAdd(&accs[5 + tid], s);
    }
  }

  // ---- fused final: last block combines ----
  __syncthreads();
  if (tid == 0) {
    __threadfence();
    int* cnt = (int*)(accs + 8);
    int old = atomicAdd(cnt, 1);
    if (old == FIN_BLKS - 1) {
      float a[8];
      #pragma unroll
      for (int q = 0; q < 8; ++q) a[q] = atomicAdd(&accs[q], 0.0f);
      const float recon_loss = a[6] / (float)NB;
      const float kld = -0.5f * a[7] / (float)NB * 10.f;
      const float penetr = 100.f * a[0] / (float)NB;
      const float npts = a[1];
      const float contact = (npts > 0.f) ? (3000.f * a[2] / ((float)NB * npts)) : 0.f;
      const float consistency = -5.f * a[3] / (npts + 0.0001f);
      const float lossh = 35.f * (1.f - 0.005f) * (a[5] / (float)(NB * NH));
      const float losso = 30.f * (1.f - 0.005f) * (a[4] / (float)(NB * NO));
      out[0] = recon_loss + 0.1f * kld + 1000.f * penetr + 10.f * contact
             + 10.f * consistency + lossh + losso;
    }
  }
}

// =========================== PATH C (tiny ws fallback) ===========================
__global__ __launch_bounds__(256) void obj_mono(
    const float* __restrict__ recon, const float* __restrict__ gt,
    const float* __restrict__ rnorm, const float* __restrict__ gnorm,
    const float* __restrict__ obj, float* __restrict__ accs)
{
  __shared__ float4 sR[NH];
  __shared__ float4 sG[NH];
  __shared__ float red[4][5];
  const int b = blockIdx.x / 12;
  const int tile = blockIdx.x % 12;
  const int tid = threadIdx.x;
  for (int i = tid; i < NH; i += 256) {
    const float* p = recon + ((size_t)b * NH + i) * 3;
    float x = p[0], y = p[1], z = p[2];
    sR[i] = make_float4(x, y, z, x*x + y*y + z*z);
    const float* q = gt + ((size_t)b * NH + i) * 3;
    float gx = q[0], gy = q[1], gz = q[2];
    sG[i] = make_float4(gx, gy, gz, gx*gx + gy*gy + gz*gz);
  }
  __syncthreads();
  const int o = tile * 256 + tid;
  float penetr = 0.f, nptsv = 0.f, contactv = 0.f, consistv = 0.f, lossov = 0.f;
  if (o < NO) {
    const float* op = obj + ((size_t)b * NO + o) * 3;
    const float ox = op[0], oy = op[1], oz = op[2];
    const float nx = -2.f*ox, ny = -2.f*oy, nz = -2.f*oz;
    const float o2 = ox*ox + oy*oy + oz*oz;
    float bR = 3.4e38f, bG = 3.4e38f; int iR = 0, iG = 0;
    for (int i = 0; i < NH; ++i) {
      float4 h = sR[i];
      float t = fmaf(nx, h.x, h.w); t = fmaf(ny, h.y, t); t = fmaf(nz, h.z, t);
      if (t < bR) { bR = t; iR = i; }
      float4 g = sG[i];
      float u = fmaf(nx, g.x, g.w); u = fmaf(ny, g.y, u); u = fmaf(nz, g.z, u);
      if (u < bG) { bG = u; iG = i; }
    }
    float bP = 3.4e38f;
    for (int k = 0; k < NP; ++k) {
      float4 h = sR[c_prior[k]];
      float t = fmaf(nx, h.x, h.w); t = fmaf(ny, h.y, t); t = fmaf(nz, h.z, t);
      bP = fminf(bP, t);
    }
    float d2R = fmaxf(bR + o2, 0.f);
    float d2G = fmaxf(bG + o2, 0.f);
    float d2P = fmaxf(bP + o2, 0.f);
    float4 hR = sR[iR];
    const float* nR = rnorm + ((size_t)b * NH + iR) * 3;
    float dotR = (ox-hR.x)*nR[0] + (oy-hR.y)*nR[1] + (oz-hR.z)*nR[2];
    float4 hG = sG[iG];
    const float* nG = gnorm + ((size_t)b * NH + iG) * 3;
    float dotG = (ox-hG.x)*nG[0] + (oy-hG.y)*nG[1] + (oz-hG.z)*nG[2];
    float sgnR = (dotR > 0.f) ? 1.f : ((dotR < 0.f) ? -1.f : 0.f);
    float sgnG = (dotG > 0.f) ? 1.f : ((dotG < 0.f) ? -1.f : 0.f);
    float sR_ = sqrtf(d2R), sG_ = sqrtf(d2G);
    float o2h = sR_*sgnR, o2hg = sG_*sgnG;
    bool interior = dotR < 0.f;
    bool cmap = sG_ < 0.005f, rcmap = sR_ < 0.005f;
    penetr = interior ? d2R : 0.f;
    nptsv = cmap ? 1.f : 0.f;
    contactv = cmap ? d2P : 0.f;
    consistv = (cmap && rcmap) ? 1.f : 0.f;
    float w = (o2h < 0.f) ? 1.5f : (((o2hg < 0.01f) && (o2hg > -0.005f)) ? 1.f : 0.1f);
    lossov = fabsf(o2h - o2hg) * w;
  }
  float vals[5] = {penetr, nptsv, contactv, consistv, lossov};
  const int lane = tid & 63, wv = tid >> 6;
  for (int q = 0; q < 5; ++q) {
    float s = wave_sum(vals[q]);
    if (lane == 0) red[wv][q] = s;
  }
  __syncthreads();
  if (tid < 5) {
    float s = red[0][tid] + red[1][tid] + red[2][tid] + red[3][tid];
    atomicAdd(&accs[tid], s);
  }
}

__global__ __launch_bounds__(256) void hand_full(
    const float* __restrict__ recon, const float* __restrict__ gt,
    const float* __restrict__ obj, const float* __restrict__ vw,
    float* __restrict__ accs)
{
  __shared__ float4 sO[500];
  __shared__ float red[4];
  const int b = blockIdx.x >> 2;
  const int j = ((blockIdx.x & 3) << 8) + threadIdx.x;
  const bool valid = j < NH;
  float rx=0,ry=0,rz=0,gx=0,gy=0,gz=0;
  if (valid) {
    const float* rp = recon + ((size_t)b * NH + j) * 3;
    const float* gp = gt + ((size_t)b * NH + j) * 3;
    rx=rp[0];ry=rp[1];rz=rp[2]; gx=gp[0];gy=gp[1];gz=gp[2];
  }
  const float nrx=-2.f*rx, nry=-2.f*ry, nrz=-2.f*rz;
  const float ngx=-2.f*gx, ngy=-2.f*gy, ngz=-2.f*gz;
  const float r2 = rx*rx+ry*ry+rz*rz, g2 = gx*gx+gy*gy+gz*gz;
  float mR = 3.4e38f, mG = 3.4e38f;
  for (int oc = 0; oc < 6; ++oc) {
    __syncthreads();
    const float* Ob = obj + ((size_t)b * NO + oc * 500) * 3;
    for (int i = threadIdx.x; i < 500; i += 256) {
      float x = Ob[3*i], y = Ob[3*i+1], z = Ob[3*i+2];
      sO[i] = make_float4(x, y, z, x*x + y*y + z*z);
    }
    __syncthreads();
    if (valid) {
      for (int k = 0; k < 500; ++k) {
        float4 o4 = sO[k];
        float t = fmaf(nrx,o4.x,o4.w); t = fmaf(nry,o4.y,t); t = fmaf(nrz,o4.z,t);
        mR = fminf(mR, t);
        float u = fmaf(ngx,o4.x,o4.w); u = fmaf(ngy,o4.y,u); u = fmaf(ngz,o4.z,u);
        mG = fminf(mG, u);
      }
    }
  }
  float lossh = valid ? fabsf(sqrtf(fmaxf(mR+r2,0.f)) - sqrtf(fmaxf(mG+g2,0.f))) * powf(vw[j], 0.4f) : 0.f;
  const int lane = threadIdx.x & 63, wv = threadIdx.x >> 6;
  float s = wave_sum(lossh);
  if (lane == 0) red[wv] = s;
  __syncthreads();
  if (threadIdx.x == 0) atomicAdd(&accs[5], red[0]+red[1]+red[2]+red[3]);
}

__global__ __launch_bounds__(256) void tail_nomins(
    const float* __restrict__ recon, const float* __restrict__ gt,
    const float* __restrict__ mean, const float* __restrict__ logv,
    float* __restrict__ accs)
{
  __shared__ float red[4][2];
  const int t = blockIdx.x * 256 + threadIdx.x;
  float rsum = 0.f, ksum = 0.f;
  if (t < NB * NH) {
    const float* rp = recon + (size_t)t * 3;
    const float* gp = gt + (size_t)t * 3;
    float d0 = rp[0]-gp[0], d1 = rp[1]-gp[1], d2 = rp[2]-gp[2];
    rsum = d0*d0 + d1*d1 + d2*d2;
  }
  if (t < NB * NZ) {
    float m = mean[t], lv = logv[t];
    ksum = 1.f + lv - m*m - expf(lv);
  }
  float vals[2] = {rsum, ksum};
  const int lane = threadIdx.x & 63, wv = threadIdx.x >> 6;
  for (int q = 0; q < 2; ++q) {
    float s = wave_sum(vals[q]);
    if (lane == 0) red[wv][q] = s;
  }
  __syncthreads();
  if (threadIdx.x < 2) {
    float s = red[0][threadIdx.x] + red[1][threadIdx.x] + red[2][threadIdx.x] + red[3][threadIdx.x];
    atomicAdd(&accs[6 + threadIdx.x], s);
  }
}

__global__ void init_small(float* accs) {
  int t = threadIdx.x;
  if (t < 8) accs[t] = 0.0f;
}

__global__ void final_fb(const float* __restrict__ a, float* __restrict__ out) {
  const float recon_loss = a[6] / (float)NB;
  const float kld = -0.5f * a[7] / (float)NB * 10.f;
  const float penetr = 100.f * a[0] / (float)NB;
  const float npts = a[1];
  const float contact = (npts > 0.f) ? (3000.f * a[2] / ((float)NB * npts)) : 0.f;
  const float consistency = -5.f * a[3] / (npts + 0.0001f);
  const float lossh = 35.f * (1.f - 0.005f) * (a[5] / (float)(NB * NH));
  const float losso = 30.f * (1.f - 0.005f) * (a[4] / (float)(NB * NO));
  out[0] = recon_loss + 0.1f*kld + 1000.f*penetr + 10.f*contact + 10.f*consistency + lossh + losso;
}

extern "C" void kernel_launch(void* const* d_in, const int* in_sizes, int n_in,
                              void* d_out, int out_size, void* d_ws, size_t ws_size,
                              hipStream_t stream) {
  const float* recon = (const float*)d_in[0];
  const float* gt    = (const float*)d_in[1];
  const float* rnorm = (const float*)d_in[2];
  const float* gnorm = (const float*)d_in[3];
  const float* obj   = (const float*)d_in[4];
  const float* mean  = (const float*)d_in[5];
  const float* logv  = (const float*)d_in[6];
  const float* vw    = (const float*)d_in[7];
  float* out = (float*)d_out;

  // ws: accs[16] @0 | slices @256: keyR[4N] keyG[4N] priorK[4N] minHR[12H] minHG[12H]
  float* accs   = (float*)d_ws;
  float* keyR   = (float*)((char*)d_ws + 256);
  float* keyG   = keyR + (size_t)JSPLIT * NKEY;
  float* priorK = keyG + (size_t)JSPLIT * NKEY;
  float* minHR  = priorK + (size_t)JSPLIT * NKEY;
  float* minHG  = minHR + (size_t)HC * NHT;
  const size_t neededA = 256 + (3ull * JSPLIT * NKEY + 2ull * HC * NHT) * sizeof(float);

  if (ws_size >= neededA) {
    mega1a<<<OBJ_BLKS + HAND_BLKS, 256, 0, stream>>>(
        recon, gt, obj, keyR, keyG, priorK, minHR, minHG, accs);
    mega2a<<<FIN_BLKS, 256, 0, stream>>>(
        recon, gt, rnorm, gnorm, obj, mean, logv, vw,
        keyR, keyG, priorK, minHR, minHG, accs, out);
  } else {
    init_small<<<1, 64, 0, stream>>>(accs);
    obj_mono<<<NB * 12, 256, 0, stream>>>(recon, gt, rnorm, gnorm, obj, accs);
    hand_full<<<NB * 4, 256, 0, stream>>>(recon, gt, obj, vw, accs);
    tail_nomins<<<(NB * NH + 255) / 256, 256, 0, stream>>>(recon, gt, mean, logv, accs);
    final_fb<<<1, 1, 0, stream>>>(accs, out);
  }
}